// Round 5
// baseline (563.999 us; speedup 1.0000x reference)
//
#include <hip/hip_runtime.h>

#define NT   198     // n_time
#define BB   32      // batch
#define CC   16      // emg channels
#define TT   8000    // emg time
#define FF   512     // conv filters
#define KW   65      // conv kernel width
#define HD   512     // hidden
#define OUT  20
#define CJ   (CC*KW) // 1040
#define TOUT 7936    // T - 64
#define NPS  50      // num_pos_steps

typedef float f4 __attribute__((ext_vector_type(4)));
typedef unsigned u2 __attribute__((ext_vector_type(2)));

// workspace layout (floats)
#define WS_CW 0
#define WS_BX (WS_CW + CJ*HD)
#define WS_X  (WS_BX + HD)
#define WS_PR (WS_X + NT*BB*HD)

// ---------------- CW[cj][h] = sum_f conv_w[f][cj] * w1[f][h] ----------------
__global__ void k_cw(const float* __restrict__ conv_w, const float* __restrict__ w1,
                     float* __restrict__ CW) {
    __shared__ float cw[32][8];
    int cj0 = blockIdx.x * 8;
    int tid = threadIdx.x;
    int hh = tid * 2;
    float acc[8][2] = {};
    for (int f0 = 0; f0 < FF; f0 += 32) {
        __syncthreads();
        int ff = tid >> 3, r = tid & 7;
        cw[ff][r] = conv_w[(f0 + ff) * CJ + cj0 + r];
        __syncthreads();
        #pragma unroll
        for (int f = 0; f < 32; ++f) {
            float wa = w1[(f0 + f) * HD + hh];
            float wb = w1[(f0 + f) * HD + hh + 1];
            #pragma unroll
            for (int r2 = 0; r2 < 8; ++r2) {
                float c = cw[f][r2];
                acc[r2][0] += c * wa;
                acc[r2][1] += c * wb;
            }
        }
    }
    for (int r2 = 0; r2 < 8; ++r2) {
        CW[(cj0 + r2) * HD + hh]     = acc[r2][0];
        CW[(cj0 + r2) * HD + hh + 1] = acc[r2][1];
    }
}

// bX[h] = b1[h] + sum_f conv_b[f] * w1[f][h]
__global__ void k_bx(const float* __restrict__ conv_b, const float* __restrict__ w1,
                     const float* __restrict__ b1, float* __restrict__ bX) {
    int h = threadIdx.x;
    float acc = b1[h];
    for (int f = 0; f < FF; ++f) acc += conv_b[f] * w1[f * HD + h];
    bX[h] = acc;
}

// ------- X[b*198+t][h] = E @ CW + bX : 64x64x32 tile, 128 thr, 8x4 micro ----
__global__ __launch_bounds__(128) void k_x4(const float* __restrict__ emg,
                                            const float* __restrict__ CW,
                                            const float* __restrict__ bX,
                                            float* __restrict__ X) {
    __shared__ float As[32][68];
    __shared__ float Bs[32][68];
    const int m0 = blockIdx.x * 64;
    const int n0 = blockIdx.y * 64;
    const int tid = threadIdx.x;
    const int tx = tid & 15, ty = tid >> 4;      // col group (4 cols), row group (8 rows)

    // A-staging: fixed row per thread, 16 consecutive kk (wave-uniform kbase)
    const int arow = tid & 63;
    const int kbase = (tid >> 6) * 16;           // 0 or 16
    const int grow = m0 + arow;                  // = b*198 + t
    const int bb = grow / NT;
    const int tt = grow - bb * NT;
    const float src = (float)tt * (7935.0f / 197.0f);
    const float fl = floorf(src);
    const int lo = (int)fl;
    const float w = src - fl;
    const int dhi = (w > 0.0f) ? 1 : 0;
    const float* ebase = emg + (size_t)bb * CC * TT + lo;
    int c = 0, j = kbase;                        // k = c*65 + j

    f4 acc[8] = {};

    for (int kt = 0; kt < 33; ++kt) {
        const int k0 = kt * 32;
        __syncthreads();
        #pragma unroll
        for (int s = 0; s < 16; ++s) {
            int js = j + s, cs = c;
            if (js >= KW) { js -= KW; cs += 1; }
            float v = 0.f;
            if (k0 + kbase + s < CJ) {
                const float* p = ebase + cs * TT + js;
                v = (1.0f - w) * p[0] + w * p[dhi];
            }
            As[kbase + s][arow] = v;
        }
        {
            int kb = tid >> 4, c4 = tid & 15;    // kb 0..7
            #pragma unroll
            for (int r = 0; r < 4; ++r) {
                int k = k0 + kb + r * 8;
                f4 bv = {0.f, 0.f, 0.f, 0.f};
                if (k < CJ) bv = *(const f4*)(CW + (size_t)k * HD + n0 + c4 * 4);
                *(f4*)&Bs[kb + r * 8][c4 * 4] = bv;
            }
        }
        __syncthreads();
        #pragma unroll
        for (int kk = 0; kk < 32; ++kk) {
            f4 a0 = *(f4*)&As[kk][ty * 8];
            f4 a1 = *(f4*)&As[kk][ty * 8 + 4];
            f4 bq = *(f4*)&Bs[kk][tx * 4];
            acc[0] += a0[0] * bq; acc[1] += a0[1] * bq;
            acc[2] += a0[2] * bq; acc[3] += a0[3] * bq;
            acc[4] += a1[0] * bq; acc[5] += a1[1] * bq;
            acc[6] += a1[2] * bq; acc[7] += a1[3] * bq;
        }
        j += 32;
        if (j >= KW) { j -= KW; c += 1; }
    }

    f4 bx = *(const f4*)(bX + n0 + tx * 4);
    #pragma unroll
    for (int i = 0; i < 8; ++i) {
        int r = m0 + ty * 8 + i;
        *(f4*)(X + (size_t)r * HD + n0 + tx * 4) = acc[i] + bx;
    }
}

// ------------- scan: 1 wave per batch, butterfly reduce-scatter -------------
// value q ends (fully 64-lane reduced) in lanes 2q, 2q+1  (q = (lane>>1)&31)
#define BF_XCHG32(i) { \
    float send = up ? v[(i)] : v[(i)+16]; \
    float keep = up ? v[(i)+16] : v[(i)]; \
    u2 rr = __builtin_amdgcn_permlane32_swap(__float_as_uint(send), __float_as_uint(send), false, false); \
    float recv = up ? __uint_as_float(rr[0]) : __uint_as_float(rr[1]); \
    v[(i)] = keep + recv; }

#define BF_XCHG_SWZ16(i) { \
    float send = up ? v[(i)] : v[(i)+8]; \
    float keep = up ? v[(i)+8] : v[(i)]; \
    float recv = __int_as_float(__builtin_amdgcn_ds_swizzle(__float_as_int(send), 0x401f)); \
    v[(i)] = keep + recv; }

#define BF_XCHG_DPP(i, half, ctrl) { \
    float send = up ? v[(i)] : v[(i)+(half)]; \
    float keep = up ? v[(i)+(half)] : v[(i)]; \
    float recv = __int_as_float(__builtin_amdgcn_mov_dpp(__float_as_int(send), ctrl, 0xf, 0xf, true)); \
    v[(i)] = keep + recv; }

#define SCAN_STEP2(T, ISPOS) { \
    int tn = (T) + 1 < NT ? (T) + 1 : NT - 1; \
    f4 xna = *(const f4*)(Xb + (size_t)tn * HD); \
    f4 xnb = *(const f4*)(Xb + (size_t)tn * HD + 4); \
    f4 ha = xca, hb = xcb; \
    _Pragma("unroll") \
    for (int jj = 0; jj < OUT; ++jj) { ha += sp[jj] * w1pa[jj]; hb += sp[jj] * w1pb[jj]; } \
    ha[0]=fmaxf(ha[0],0.f); ha[1]=fmaxf(ha[1],0.f); ha[2]=fmaxf(ha[2],0.f); ha[3]=fmaxf(ha[3],0.f); \
    hb[0]=fmaxf(hb[0],0.f); hb[1]=fmaxf(hb[1],0.f); hb[2]=fmaxf(hb[2],0.f); hb[3]=fmaxf(hb[3],0.f); \
    float v[32]; \
    _Pragma("unroll") \
    for (int g = 0; g < 5; ++g) { \
        f4 a = ha[0] * w2r[0][g]; \
        a += ha[1] * w2r[1][g]; a += ha[2] * w2r[2][g]; a += ha[3] * w2r[3][g]; \
        a += hb[0] * w2r[4][g]; a += hb[1] * w2r[5][g]; \
        a += hb[2] * w2r[6][g]; a += hb[3] * w2r[7][g]; \
        v[g*4+0] = a[0]; v[g*4+1] = a[1]; v[g*4+2] = a[2]; v[g*4+3] = a[3]; } \
    _Pragma("unroll") \
    for (int i = OUT; i < 32; ++i) v[i] = 0.f; \
    { bool up = (lane & 32) != 0; \
      BF_XCHG32(0) BF_XCHG32(1) BF_XCHG32(2)  BF_XCHG32(3) \
      BF_XCHG32(4) BF_XCHG32(5) BF_XCHG32(6)  BF_XCHG32(7) \
      BF_XCHG32(8) BF_XCHG32(9) BF_XCHG32(10) BF_XCHG32(11) \
      BF_XCHG32(12) BF_XCHG32(13) BF_XCHG32(14) BF_XCHG32(15) } \
    { bool up = (lane & 16) != 0; \
      BF_XCHG_SWZ16(0) BF_XCHG_SWZ16(1) BF_XCHG_SWZ16(2) BF_XCHG_SWZ16(3) \
      BF_XCHG_SWZ16(4) BF_XCHG_SWZ16(5) BF_XCHG_SWZ16(6) BF_XCHG_SWZ16(7) } \
    { bool up = (lane & 8) != 0; \
      BF_XCHG_DPP(0, 4, 0x140) BF_XCHG_DPP(1, 4, 0x140) \
      BF_XCHG_DPP(2, 4, 0x140) BF_XCHG_DPP(3, 4, 0x140) } \
    { bool up = (lane & 4) != 0; \
      BF_XCHG_DPP(0, 2, 0x141) BF_XCHG_DPP(1, 2, 0x141) } \
    { bool up = (lane & 2) != 0; \
      BF_XCHG_DPP(0, 1, 0x4E) } \
    v[0] += __int_as_float(__builtin_amdgcn_mov_dpp(__float_as_int(v[0]), 0xB1, 0xf, 0xf, true)); \
    float outv = v[0] + b2own; \
    float pr = (ISPOS) ? outv : myprev + outv; \
    myprev = pr; \
    if (!(lane & 1) && lane < 2 * OUT) predrow[(size_t)(T) * OUT + (lane >> 1)] = pr; \
    _Pragma("unroll") \
    for (int jj = 0; jj < OUT; ++jj) \
        sp[jj] = __uint_as_float(__builtin_amdgcn_readlane(__float_as_uint(pr), 2 * jj)); \
    xca = xna; xcb = xnb; }

__global__ __launch_bounds__(64, 1) void k_scan(
        const float* __restrict__ X, const float* __restrict__ w1,
        const float* __restrict__ w2, const float* __restrict__ b2,
        const float* __restrict__ jang, const int* __restrict__ provide,
        float* __restrict__ preds) {
    const int b = blockIdx.x;
    const int lane = threadIdx.x;                // 0..63
    const int h0 = lane * 8;                     // 8 contiguous h per lane
    const int q = lane >> 1;

    f4 w1pa[OUT], w1pb[OUT];
    #pragma unroll
    for (int jj = 0; jj < OUT; ++jj) {
        w1pa[jj] = *(const f4*)(w1 + (size_t)(FF + jj) * HD + h0);
        w1pb[jj] = *(const f4*)(w1 + (size_t)(FF + jj) * HD + h0 + 4);
    }
    f4 w2r[8][5];                                // pos half first
    #pragma unroll
    for (int i = 0; i < 8; ++i)
        #pragma unroll
        for (int g = 0; g < 5; ++g)
            w2r[i][g] = *(const f4*)(w2 + (size_t)(h0 + i) * (2 * OUT) + g * 4);

    float b2own_pos = (lane < 2 * OUT) ? b2[q] : 0.f;
    float b2own_vel = (lane < 2 * OUT) ? b2[OUT + q] : 0.f;

    float myprev = 0.f;
    if (lane < 2 * OUT && provide[0])
        myprev = jang[((size_t)(b * OUT + q)) * TT + 32];
    float sp[OUT];
    #pragma unroll
    for (int jj = 0; jj < OUT; ++jj)
        sp[jj] = __uint_as_float(__builtin_amdgcn_readlane(__float_as_uint(myprev), 2 * jj));

    const float* Xb = X + (size_t)b * NT * HD + h0;
    float* predrow = preds + (size_t)b * NT * OUT;
    f4 xca = *(const f4*)(Xb);
    f4 xcb = *(const f4*)(Xb + 4);

    float b2own = b2own_pos;
    for (int t = 0; t < NPS; ++t) { SCAN_STEP2(t, true) }

    // switch to velocity half of w2 / b2
    #pragma unroll
    for (int i = 0; i < 8; ++i)
        #pragma unroll
        for (int g = 0; g < 5; ++g)
            w2r[i][g] = *(const f4*)(w2 + (size_t)(h0 + i) * (2 * OUT) + OUT + g * 4);
    b2own = b2own_vel;
    for (int t = NPS; t < NT; ++t) { SCAN_STEP2(t, false) }
}

// ---------------- output kernels ----------------
__global__ void k_up(const float* __restrict__ preds, float* __restrict__ outp) {
    __shared__ float row[NT];
    int rc = blockIdx.x;  // b*20 + ch
    int bq = rc / OUT, ch = rc - bq * OUT;
    int tid = threadIdx.x;
    if (tid < NT) row[tid] = preds[(size_t)(bq * NT + tid) * OUT + ch];
    __syncthreads();
    const float scale = (float)NT / (float)TOUT;
    for (int i = tid; i < TOUT; i += 256) {
        float src = ((float)i + 0.5f) * scale - 0.5f;
        src = fminf(fmaxf(src, 0.0f), (float)(NT - 1));
        float fl = floorf(src);
        int lo = (int)fl;
        int hi = lo + 1; if (hi > NT - 1) hi = NT - 1;
        float w = src - fl;
        outp[(size_t)rc * TOUT + i] = row[lo] * (1.0f - w) + row[hi] * w;
    }
}

__global__ void k_ja(const float* __restrict__ jang, float* __restrict__ outp) {
    int rc = blockIdx.x;
    int tid = threadIdx.x;
    for (int i = tid; i < TOUT; i += 256)
        outp[(size_t)rc * TOUT + i] = jang[(size_t)rc * TT + 32 + i];
}

__global__ void k_mask(const unsigned char* __restrict__ m, float* __restrict__ outp) {
    int b = blockIdx.x;
    int tid = threadIdx.x;
    for (int i = tid; i < TOUT; i += 256)
        outp[(size_t)b * TOUT + i] = m[(size_t)b * TT + 32 + i] ? 1.0f : 0.0f;
}

extern "C" void kernel_launch(void* const* d_in, const int* in_sizes, int n_in,
                              void* d_out, int out_size, void* d_ws, size_t ws_size,
                              hipStream_t stream) {
    const float* emg     = (const float*)d_in[0];
    const float* jang    = (const float*)d_in[1];
    const unsigned char* msk = (const unsigned char*)d_in[2];
    const int*   provide = (const int*)d_in[3];
    const float* conv_w  = (const float*)d_in[4];
    const float* conv_b  = (const float*)d_in[5];
    const float* w1      = (const float*)d_in[6];
    const float* b1      = (const float*)d_in[7];
    const float* w2      = (const float*)d_in[8];
    const float* b2      = (const float*)d_in[9];
    float* out = (float*)d_out;
    float* ws  = (float*)d_ws;

    float* CW    = ws + WS_CW;
    float* bX    = ws + WS_BX;
    float* X     = ws + WS_X;
    float* preds = ws + WS_PR;

    hipLaunchKernelGGL(k_cw,   dim3(CJ / 8), dim3(256), 0, stream, conv_w, w1, CW);
    hipLaunchKernelGGL(k_bx,   dim3(1),      dim3(HD),  0, stream, conv_b, w1, b1, bX);
    hipLaunchKernelGGL(k_x4,   dim3(99, 8),  dim3(128), 0, stream, emg, CW, bX, X);
    hipLaunchKernelGGL(k_scan, dim3(BB),     dim3(64),  0, stream, X, w1, w2, b2, jang, provide, preds);
    hipLaunchKernelGGL(k_up,   dim3(BB * OUT), dim3(256), 0, stream, preds, out);
    hipLaunchKernelGGL(k_ja,   dim3(BB * OUT), dim3(256), 0, stream, jang, out + (size_t)BB * OUT * TOUT);
    hipLaunchKernelGGL(k_mask, dim3(BB),     dim3(256), 0, stream, msk, out + (size_t)2 * BB * OUT * TOUT);
}

// Round 6
// 388.589 us; speedup vs baseline: 1.4514x; 1.4514x over previous
//
#include <hip/hip_runtime.h>

#define NT   198     // n_time
#define BB   32      // batch
#define CC   16      // emg channels
#define TT   8000    // emg time
#define FF   512     // conv filters
#define KW   65      // conv kernel width
#define HD   512     // hidden
#define OUT  20
#define CJ   (CC*KW) // 1040
#define KP   1056    // K padded to 33*32
#define MM   (NT*BB) // 6336
#define TOUT 7936    // T - 64
#define NPS  50      // num_pos_steps

typedef float f4 __attribute__((ext_vector_type(4)));
typedef unsigned u2 __attribute__((ext_vector_type(2)));

// workspace layout (floats); total = 10,594,560 floats = 42.4 MB
#define WS_CW 0
#define WS_BX (WS_CW + CJ*HD)        // 532480
#define WS_X  (WS_BX + HD)           // 532992
#define WS_PR (WS_X  + MM*HD)        // 3777024
#define WS_ET (WS_PR + MM*OUT)       // 3903744

// ---- Et[k][row] = interp'd conv input, transposed (row = b*198 + t) ----
__global__ void k_e(const float* __restrict__ emg, float* __restrict__ Et) {
    int k = blockIdx.x;                       // 0..KP-1
    int row = blockIdx.y * 256 + threadIdx.x; // 0..6399
    if (row >= MM) return;
    float v = 0.f;
    if (k < CJ) {
        int c = k / KW, j = k - c * KW;
        int bq = row / NT, t = row - bq * NT;
        float src = (float)t * (7935.0f / 197.0f);
        float fl = floorf(src);
        int lo = (int)fl;
        float w = src - fl;
        const float* p = emg + (size_t)(bq * CC + c) * TT + lo + j;
        v = (1.0f - w) * p[0] + w * p[(w > 0.f) ? 1 : 0];
    }
    Et[(size_t)k * MM + row] = v;
}

// ---- CW[cj][h] = sum_f conv_w[f][cj] * w1[f][h] : tiled GEMM ----
__global__ __launch_bounds__(256) void k_cw2(const float* __restrict__ cwraw,
                                             const float* __restrict__ w1,
                                             float* __restrict__ CW) {
    __shared__ float As[32][68];
    __shared__ float Bs[32][68];
    const int m0 = blockIdx.x * 64;           // cj
    const int n0 = blockIdx.y * 64;           // h
    const int tid = threadIdx.x;
    const int tx = tid & 15, ty = tid >> 4;
    const int am = tid & 63;
    const int kb8 = (tid >> 6) * 8;
    const int mrow = m0 + am;
    const int mclamp = mrow < CJ ? mrow : CJ - 1;

    f4 acc[4] = {};
    for (int k0 = 0; k0 < FF; k0 += 32) {
        __syncthreads();
        #pragma unroll
        for (int s = 0; s < 8; ++s)
            As[kb8 + s][am] = cwraw[(size_t)(k0 + kb8 + s) * CJ + mclamp];
        {
            int kb = tid >> 4, c4 = tid & 15;
            *(f4*)&Bs[kb][c4 * 4]      = *(const f4*)(w1 + (size_t)(k0 + kb) * HD + n0 + c4 * 4);
            *(f4*)&Bs[kb + 16][c4 * 4] = *(const f4*)(w1 + (size_t)(k0 + kb + 16) * HD + n0 + c4 * 4);
        }
        __syncthreads();
        #pragma unroll
        for (int kk = 0; kk < 32; ++kk) {
            f4 a = *(f4*)&As[kk][ty * 4];
            f4 bq = *(f4*)&Bs[kk][tx * 4];
            acc[0] += a[0] * bq; acc[1] += a[1] * bq;
            acc[2] += a[2] * bq; acc[3] += a[3] * bq;
        }
    }
    #pragma unroll
    for (int i = 0; i < 4; ++i) {
        int r = m0 + ty * 4 + i;
        if (r < CJ) *(f4*)(CW + (size_t)r * HD + n0 + tx * 4) = acc[i];
    }
}

// bX[h] = b1[h] + sum_f conv_b[f] * w1[f][h]
__global__ void k_bx(const float* __restrict__ conv_b, const float* __restrict__ w1,
                     const float* __restrict__ b1, float* __restrict__ bX) {
    int h = threadIdx.x;
    float acc = b1[h];
    for (int f = 0; f < FF; ++f) acc += conv_b[f] * w1[f * HD + h];
    bX[h] = acc;
}

// ---- X[row][h] = Et[:,row] @ CW + bX : 64x64x32 tile, coalesced A ----
__global__ __launch_bounds__(256) void k_x5(const float* __restrict__ Et,
                                            const float* __restrict__ CW,
                                            const float* __restrict__ bX,
                                            float* __restrict__ X) {
    __shared__ float As[32][68];
    __shared__ float Bs[32][68];
    const int m0 = blockIdx.x * 64;   // 99 blocks
    const int n0 = blockIdx.y * 64;   // 8 blocks
    const int tid = threadIdx.x;
    const int tx = tid & 15, ty = tid >> 4;
    const int am = tid & 63;
    const int kb8 = (tid >> 6) * 8;

    f4 acc[4] = {};
    for (int k0 = 0; k0 < KP; k0 += 32) {
        __syncthreads();
        #pragma unroll
        for (int s = 0; s < 8; ++s)
            As[kb8 + s][am] = Et[(size_t)(k0 + kb8 + s) * MM + m0 + am];
        {
            int kb = tid >> 4, c4 = tid & 15;
            int k = k0 + kb;
            f4 bv = {0.f, 0.f, 0.f, 0.f};
            if (k < CJ) bv = *(const f4*)(CW + (size_t)k * HD + n0 + c4 * 4);
            *(f4*)&Bs[kb][c4 * 4] = bv;
            int k2 = k + 16;
            f4 bv2 = {0.f, 0.f, 0.f, 0.f};
            if (k2 < CJ) bv2 = *(const f4*)(CW + (size_t)k2 * HD + n0 + c4 * 4);
            *(f4*)&Bs[kb + 16][c4 * 4] = bv2;
        }
        __syncthreads();
        #pragma unroll
        for (int kk = 0; kk < 32; ++kk) {
            f4 a = *(f4*)&As[kk][ty * 4];
            f4 bq = *(f4*)&Bs[kk][tx * 4];
            acc[0] += a[0] * bq; acc[1] += a[1] * bq;
            acc[2] += a[2] * bq; acc[3] += a[3] * bq;
        }
    }
    f4 bx = *(const f4*)(bX + n0 + tx * 4);
    #pragma unroll
    for (int i = 0; i < 4; ++i)
        *(f4*)(X + (size_t)(m0 + ty * 4 + i) * HD + n0 + tx * 4) = acc[i] + bx;
}

// ---- butterfly reduce-scatter primitives (proven in R5) ----
#define BF_XCHG32(i) { \
    float send = up ? v[(i)] : v[(i)+16]; \
    float keep = up ? v[(i)+16] : v[(i)]; \
    u2 rr = __builtin_amdgcn_permlane32_swap(__float_as_uint(send), __float_as_uint(send), false, false); \
    float recv = up ? __uint_as_float(rr[0]) : __uint_as_float(rr[1]); \
    v[(i)] = keep + recv; }

#define BF_XCHG_SWZ16(i) { \
    float send = up ? v[(i)] : v[(i)+8]; \
    float keep = up ? v[(i)+8] : v[(i)]; \
    float recv = __int_as_float(__builtin_amdgcn_ds_swizzle(__float_as_int(send), 0x401f)); \
    v[(i)] = keep + recv; }

#define BF_XCHG_DPP(i, half, ctrl) { \
    float send = up ? v[(i)] : v[(i)+(half)]; \
    float keep = up ? v[(i)+(half)] : v[(i)]; \
    float recv = __int_as_float(__builtin_amdgcn_mov_dpp(__float_as_int(send), ctrl, 0xf, 0xf, true)); \
    v[(i)] = keep + recv; }

// ---- scan: 2 waves/block, 4 h/lane, 1 barrier/step, all weights in regs ----
#define SCAN_STEP3(T, ISPOS) { \
    int tn = (T) + 1 < NT ? (T) + 1 : NT - 1; \
    f4 xf = *(const f4*)(Xb + (size_t)tn * HD); \
    f4 hca = xc, hcb = {0.f, 0.f, 0.f, 0.f}; \
    _Pragma("unroll") \
    for (int jj = 0; jj < OUT; jj += 2) { \
        hca += prevv[jj >> 2][jj & 3] * w1p[jj]; \
        hcb += prevv[(jj + 1) >> 2][(jj + 1) & 3] * w1p[jj + 1]; } \
    f4 h = hca + hcb; \
    h[0] = fmaxf(h[0], 0.f); h[1] = fmaxf(h[1], 0.f); \
    h[2] = fmaxf(h[2], 0.f); h[3] = fmaxf(h[3], 0.f); \
    float v[32]; \
    _Pragma("unroll") \
    for (int g = 0; g < 5; ++g) { \
        f4 a = h[0] * w2r[0][g]; \
        a += h[1] * w2r[1][g]; a += h[2] * w2r[2][g]; a += h[3] * w2r[3][g]; \
        v[g*4+0] = a[0]; v[g*4+1] = a[1]; v[g*4+2] = a[2]; v[g*4+3] = a[3]; } \
    _Pragma("unroll") \
    for (int i = OUT; i < 32; ++i) v[i] = 0.f; \
    { bool up = (lane & 32) != 0; \
      BF_XCHG32(0) BF_XCHG32(1) BF_XCHG32(2)  BF_XCHG32(3) \
      BF_XCHG32(4) BF_XCHG32(5) BF_XCHG32(6)  BF_XCHG32(7) \
      BF_XCHG32(8) BF_XCHG32(9) BF_XCHG32(10) BF_XCHG32(11) \
      BF_XCHG32(12) BF_XCHG32(13) BF_XCHG32(14) BF_XCHG32(15) } \
    { bool up = (lane & 16) != 0; \
      BF_XCHG_SWZ16(0) BF_XCHG_SWZ16(1) BF_XCHG_SWZ16(2) BF_XCHG_SWZ16(3) \
      BF_XCHG_SWZ16(4) BF_XCHG_SWZ16(5) BF_XCHG_SWZ16(6) BF_XCHG_SWZ16(7) } \
    { bool up = (lane & 8) != 0; \
      BF_XCHG_DPP(0, 4, 0x140) BF_XCHG_DPP(1, 4, 0x140) \
      BF_XCHG_DPP(2, 4, 0x140) BF_XCHG_DPP(3, 4, 0x140) } \
    { bool up = (lane & 4) != 0; \
      BF_XCHG_DPP(0, 2, 0x141) BF_XCHG_DPP(1, 2, 0x141) } \
    { bool up = (lane & 2) != 0; \
      BF_XCHG_DPP(0, 1, 0x4E) } \
    v[0] += __int_as_float(__builtin_amdgcn_mov_dpp(__float_as_int(v[0]), 0xB1, 0xf, 0xf, true)); \
    if (!(lane & 1) && lane < 2 * OUT) part[(T) & 1][wv][lane >> 1] = v[0] + b2own; \
    __syncthreads(); \
    _Pragma("unroll") \
    for (int g = 0; g < 5; ++g) { \
        f4 pa = *(f4*)&part[(T) & 1][0][g * 4]; \
        f4 pb = *(f4*)&part[(T) & 1][1][g * 4]; \
        f4 sm = pa + pb; \
        prevv[g] = (ISPOS) ? sm : (prevv[g] + sm); } \
    if (tid == 0) { \
        _Pragma("unroll") \
        for (int g = 0; g < 5; ++g) \
            *(f4*)(predrow + (size_t)(T) * OUT + g * 4) = prevv[g]; } \
    xc = xf; }

__global__ __launch_bounds__(128, 1) void k_scan(
        const float* __restrict__ X, const float* __restrict__ w1,
        const float* __restrict__ w2, const float* __restrict__ b2,
        const float* __restrict__ jang, const int* __restrict__ provide,
        float* __restrict__ preds) {
    __shared__ __align__(16) float part[2][2][24];
    const int b = blockIdx.x;
    const int tid = threadIdx.x;
    const int lane = tid & 63, wv = tid >> 6;
    const int h0 = wv * 256 + lane * 4;       // 4 contiguous h per lane

    f4 w1p[OUT];
    #pragma unroll
    for (int jj = 0; jj < OUT; ++jj)
        w1p[jj] = *(const f4*)(w1 + (size_t)(FF + jj) * HD + h0);

    f4 w2r[4][5];                             // pos half first
    #pragma unroll
    for (int i = 0; i < 4; ++i)
        #pragma unroll
        for (int g = 0; g < 5; ++g)
            w2r[i][g] = *(const f4*)(w2 + (size_t)(h0 + i) * (2 * OUT) + g * 4);

    float b2own = 0.f;
    if (wv == 1 && !(lane & 1) && lane < 2 * OUT) b2own = b2[lane >> 1];

    // prev held redundantly in ALL lanes as f4[5]
    float pvf = provide[0] ? 1.0f : 0.0f;
    f4 prevv[5];
    #pragma unroll
    for (int g = 0; g < 5; ++g)
        #pragma unroll
        for (int e = 0; e < 4; ++e)
            prevv[g][e] = pvf * jang[(size_t)(b * OUT + g * 4 + e) * TT + 32];

    const float* Xb = X + (size_t)b * NT * HD + h0;
    float* predrow = preds + (size_t)b * NT * OUT;
    f4 xc = *(const f4*)(Xb);

    for (int t = 0; t < NPS; ++t) { SCAN_STEP3(t, true) }

    // switch to velocity half of w2 / b2
    #pragma unroll
    for (int i = 0; i < 4; ++i)
        #pragma unroll
        for (int g = 0; g < 5; ++g)
            w2r[i][g] = *(const f4*)(w2 + (size_t)(h0 + i) * (2 * OUT) + OUT + g * 4);
    b2own = 0.f;
    if (wv == 1 && !(lane & 1) && lane < 2 * OUT) b2own = b2[OUT + (lane >> 1)];

    for (int t = NPS; t < NT; ++t) { SCAN_STEP3(t, false) }
}

// ---------------- output kernels ----------------
__global__ void k_up(const float* __restrict__ preds, float* __restrict__ outp) {
    __shared__ float row[NT];
    int rc = blockIdx.x;  // b*20 + ch
    int bq = rc / OUT, ch = rc - bq * OUT;
    int tid = threadIdx.x;
    if (tid < NT) row[tid] = preds[(size_t)(bq * NT + tid) * OUT + ch];
    __syncthreads();
    const float scale = (float)NT / (float)TOUT;
    for (int i = tid; i < TOUT; i += 256) {
        float src = ((float)i + 0.5f) * scale - 0.5f;
        src = fminf(fmaxf(src, 0.0f), (float)(NT - 1));
        float fl = floorf(src);
        int lo = (int)fl;
        int hi = lo + 1; if (hi > NT - 1) hi = NT - 1;
        float w = src - fl;
        outp[(size_t)rc * TOUT + i] = row[lo] * (1.0f - w) + row[hi] * w;
    }
}

__global__ void k_ja(const float* __restrict__ jang, float* __restrict__ outp) {
    int rc = blockIdx.x;
    int tid = threadIdx.x;
    for (int i = tid; i < TOUT; i += 256)
        outp[(size_t)rc * TOUT + i] = jang[(size_t)rc * TT + 32 + i];
}

__global__ void k_mask(const unsigned char* __restrict__ m, float* __restrict__ outp) {
    int b = blockIdx.x;
    int tid = threadIdx.x;
    for (int i = tid; i < TOUT; i += 256)
        outp[(size_t)b * TOUT + i] = m[(size_t)b * TT + 32 + i] ? 1.0f : 0.0f;
}

extern "C" void kernel_launch(void* const* d_in, const int* in_sizes, int n_in,
                              void* d_out, int out_size, void* d_ws, size_t ws_size,
                              hipStream_t stream) {
    const float* emg     = (const float*)d_in[0];
    const float* jang    = (const float*)d_in[1];
    const unsigned char* msk = (const unsigned char*)d_in[2];
    const int*   provide = (const int*)d_in[3];
    const float* conv_w  = (const float*)d_in[4];
    const float* conv_b  = (const float*)d_in[5];
    const float* w1      = (const float*)d_in[6];
    const float* b1      = (const float*)d_in[7];
    const float* w2      = (const float*)d_in[8];
    const float* b2      = (const float*)d_in[9];
    float* out = (float*)d_out;
    float* ws  = (float*)d_ws;

    float* CW    = ws + WS_CW;
    float* bX    = ws + WS_BX;
    float* X     = ws + WS_X;
    float* preds = ws + WS_PR;
    float* Et    = ws + WS_ET;

    hipLaunchKernelGGL(k_e,    dim3(KP, (MM + 255) / 256), dim3(256), 0, stream, emg, Et);
    hipLaunchKernelGGL(k_cw2,  dim3((CJ + 63) / 64, HD / 64), dim3(256), 0, stream, conv_w, w1, CW);
    hipLaunchKernelGGL(k_bx,   dim3(1), dim3(HD), 0, stream, conv_b, w1, b1, bX);
    hipLaunchKernelGGL(k_x5,   dim3(MM / 64, HD / 64), dim3(256), 0, stream, Et, CW, bX, X);
    hipLaunchKernelGGL(k_scan, dim3(BB), dim3(128), 0, stream, X, w1, w2, b2, jang, provide, preds);
    hipLaunchKernelGGL(k_up,   dim3(BB * OUT), dim3(256), 0, stream, preds, out);
    hipLaunchKernelGGL(k_ja,   dim3(BB * OUT), dim3(256), 0, stream, jang, out + (size_t)BB * OUT * TOUT);
    hipLaunchKernelGGL(k_mask, dim3(BB), dim3(256), 0, stream, msk, out + (size_t)2 * BB * OUT * TOUT);
}

// Round 7
// 373.462 us; speedup vs baseline: 1.5102x; 1.0405x over previous
//
#include <hip/hip_runtime.h>

#define NT   198     // n_time
#define BB   32      // batch
#define CC   16      // emg channels
#define TT   8000    // emg time
#define FF   512     // conv filters
#define KW   65      // conv kernel width
#define HD   512     // hidden
#define OUT  20
#define CJ   (CC*KW) // 1040
#define KP   1056    // K padded to 33*32
#define MM   (NT*BB) // 6336
#define TOUT 7936    // T - 64
#define NPS  50      // num_pos_steps

typedef float f4 __attribute__((ext_vector_type(4)));

// workspace layout (floats); total = 10,615,040 floats = 42.5 MB
#define WS_CW 0
#define WS_BX (WS_CW + CJ*HD)        // 532480
#define WS_X  (WS_BX + HD)           // 532992
#define WS_PR (WS_X  + MM*HD)        // 3777024
#define WS_ET (WS_PR + MM*OUT)       // 3903744
#define WS_W2T (WS_ET + KP*MM)       // 10594560

// ---- Et[k][row] = interp'd conv input, transposed (row = b*198 + t) ----
__global__ void k_e(const float* __restrict__ emg, float* __restrict__ Et) {
    int k = blockIdx.x;                       // 0..KP-1
    int row = blockIdx.y * 256 + threadIdx.x;
    if (row >= MM) return;
    float v = 0.f;
    if (k < CJ) {
        int c = k / KW, j = k - c * KW;
        int bq = row / NT, t = row - bq * NT;
        float src = (float)t * (7935.0f / 197.0f);
        float fl = floorf(src);
        int lo = (int)fl;
        float w = src - fl;
        const float* p = emg + (size_t)(bq * CC + c) * TT + lo + j;
        v = (1.0f - w) * p[0] + w * p[(w > 0.f) ? 1 : 0];
    }
    Et[(size_t)k * MM + row] = v;
}

// ---- CW[cj][h] = sum_f conv_w[f][cj] * w1[f][h] : tiled GEMM ----
__global__ __launch_bounds__(256) void k_cw2(const float* __restrict__ cwraw,
                                             const float* __restrict__ w1,
                                             float* __restrict__ CW) {
    __shared__ float As[32][68];
    __shared__ float Bs[32][68];
    const int m0 = blockIdx.x * 64;           // cj
    const int n0 = blockIdx.y * 64;           // h
    const int tid = threadIdx.x;
    const int tx = tid & 15, ty = tid >> 4;
    const int am = tid & 63;
    const int kb8 = (tid >> 6) * 8;
    const int mrow = m0 + am;
    const int mclamp = mrow < CJ ? mrow : CJ - 1;

    f4 acc[4] = {};
    for (int k0 = 0; k0 < FF; k0 += 32) {
        __syncthreads();
        #pragma unroll
        for (int s = 0; s < 8; ++s)
            As[kb8 + s][am] = cwraw[(size_t)(k0 + kb8 + s) * CJ + mclamp];
        {
            int kb = tid >> 4, c4 = tid & 15;
            *(f4*)&Bs[kb][c4 * 4]      = *(const f4*)(w1 + (size_t)(k0 + kb) * HD + n0 + c4 * 4);
            *(f4*)&Bs[kb + 16][c4 * 4] = *(const f4*)(w1 + (size_t)(k0 + kb + 16) * HD + n0 + c4 * 4);
        }
        __syncthreads();
        #pragma unroll
        for (int kk = 0; kk < 32; ++kk) {
            f4 a = *(f4*)&As[kk][ty * 4];
            f4 bq = *(f4*)&Bs[kk][tx * 4];
            acc[0] += a[0] * bq; acc[1] += a[1] * bq;
            acc[2] += a[2] * bq; acc[3] += a[3] * bq;
        }
    }
    #pragma unroll
    for (int i = 0; i < 4; ++i) {
        int r = m0 + ty * 4 + i;
        if (r < CJ) *(f4*)(CW + (size_t)r * HD + n0 + tx * 4) = acc[i];
    }
}

// bX[h] = b1[h] + sum_f conv_b[f] * w1[f][h]
__global__ void k_bx(const float* __restrict__ conv_b, const float* __restrict__ w1,
                     const float* __restrict__ b1, float* __restrict__ bX) {
    int h = threadIdx.x;
    float acc = b1[h];
    for (int f = 0; f < FF; ++f) acc += conv_b[f] * w1[f * HD + h];
    bX[h] = acc;
}

// ---- w2t[q][h] = w2[h][q]  (q = 0..39) ----
__global__ void k_w2t(const float* __restrict__ w2, float* __restrict__ w2t) {
    int q = blockIdx.x;
    int h = threadIdx.x;
    w2t[(size_t)q * HD + h] = w2[(size_t)h * (2 * OUT) + q];
}

// ---- X[row][h] = Et[:,row] @ CW + bX : 64x64x32 tile, 128 thr, 4x8 micro ----
__global__ __launch_bounds__(128) void k_x6(const float* __restrict__ Et,
                                            const float* __restrict__ CW,
                                            const float* __restrict__ bX,
                                            float* __restrict__ X) {
    __shared__ float As[32][68];
    __shared__ float Bs[32][68];
    const int m0 = blockIdx.x * 64;   // 99 blocks
    const int n0 = blockIdx.y * 64;   // 8 blocks
    const int tid = threadIdx.x;
    const int tm = tid >> 3;          // 0..15 (4 rows each)
    const int tn = tid & 7;           // 0..7  (8 cols each)
    const int cidx = tid & 15, krb = tid >> 4;

    f4 acc0[4] = {}, acc1[4] = {};
    for (int k0 = 0; k0 < KP; k0 += 32) {
        __syncthreads();
        #pragma unroll
        for (int s = 0; s < 4; ++s) {
            int kr = krb + s * 8;
            *(f4*)&As[kr][cidx * 4] = *(const f4*)(Et + (size_t)(k0 + kr) * MM + m0 + cidx * 4);
            int k = k0 + kr;
            f4 bv = {0.f, 0.f, 0.f, 0.f};
            if (k < CJ) bv = *(const f4*)(CW + (size_t)k * HD + n0 + cidx * 4);
            *(f4*)&Bs[kr][cidx * 4] = bv;
        }
        __syncthreads();
        #pragma unroll
        for (int kk = 0; kk < 32; ++kk) {
            f4 av = *(const f4*)&As[kk][tm * 4];
            f4 b0 = *(const f4*)&Bs[kk][tn * 8];
            f4 b1 = *(const f4*)&Bs[kk][tn * 8 + 4];
            acc0[0] += av[0] * b0; acc1[0] += av[0] * b1;
            acc0[1] += av[1] * b0; acc1[1] += av[1] * b1;
            acc0[2] += av[2] * b0; acc1[2] += av[2] * b1;
            acc0[3] += av[3] * b0; acc1[3] += av[3] * b1;
        }
    }
    f4 bx0 = *(const f4*)(bX + n0 + tn * 8);
    f4 bx1 = *(const f4*)(bX + n0 + tn * 8 + 4);
    #pragma unroll
    for (int i = 0; i < 4; ++i) {
        size_t off = (size_t)(m0 + tm * 4 + i) * HD + n0 + tn * 8;
        *(f4*)(X + off)     = acc0[i] + bx0;
        *(f4*)(X + off + 4) = acc1[i] + bx1;
    }
}

// ---- scan: 320 thr. Phase A: 256 lanes x 2h. Phase B: 20 groups x 16 lanes ----
#define DPPADD(x, ctrl) ((x) + __int_as_float(__builtin_amdgcn_mov_dpp(__float_as_int(x), (ctrl), 0xf, 0xf, true)))

#define SCAN_STEP(T, ISPOS) { \
    if (aown) { \
        int tp = (T) + 2; if (tp > NT - 1) tp = NT - 1; \
        float2 xf = *(const float2*)(Xrow + (size_t)tp * HD); \
        f4 pp[5]; \
        _Pragma("unroll") \
        for (int g = 0; g < 5; ++g) pp[g] = *(const f4*)&prev_lds[(T) & 1][g * 4]; \
        float h0 = xc.x, h1 = xc.y; \
        _Pragma("unroll") \
        for (int j = 0; j < OUT; ++j) { \
            float pj = pp[j >> 2][j & 3]; \
            h0 = fmaf(pj, w1p[j].x, h0); h1 = fmaf(pj, w1p[j].y, h1); } \
        h0 = fmaxf(h0, 0.f); h1 = fmaxf(h1, 0.f); \
        float2 hw; hw.x = h0; hw.y = h1; \
        *(float2*)&h_lds[(T) & 1][tid >> 4][(2 * tid) & 31] = hw; \
        xc = xn; xn = xf; \
    } \
    __syncthreads(); \
    f4 a = {0.f, 0.f, 0.f, 0.f}; \
    _Pragma("unroll") \
    for (int s = 0; s < 8; ++s) { \
        f4 hv = *(const f4*)&h_lds[(T) & 1][r][s * 4]; \
        a += hv * ((ISPOS) ? wqp[s] : wqv[s]); } \
    float sum = (a[0] + a[1]) + (a[2] + a[3]); \
    sum = DPPADD(sum, 0xB1);   /* xor1  */ \
    sum = DPPADD(sum, 0x4E);   /* xor2  */ \
    sum = DPPADD(sum, 0x141);  /* xor7  */ \
    sum = DPPADD(sum, 0x140);  /* xor15 */ \
    float outv = sum + ((ISPOS) ? b2p : b2v); \
    myq = (ISPOS) ? outv : (myq + outv); \
    if (r == 0) { \
        predrow[(size_t)(T) * OUT + q] = myq; \
        prev_lds[((T) + 1) & 1][q] = myq; } \
    __syncthreads(); }

__global__ __launch_bounds__(320, 1) void k_scan(
        const float* __restrict__ X, const float* __restrict__ w1,
        const float* __restrict__ w2t, const float* __restrict__ b2,
        const float* __restrict__ jang, const int* __restrict__ provide,
        float* __restrict__ preds) {
    __shared__ float h_lds[2][16][36];             // padded: stride 36 dwords
    __shared__ __align__(16) float prev_lds[2][20];
    const int b = blockIdx.x;
    const int tid = threadIdx.x;
    const int q = tid >> 4;        // 0..19
    const int r = tid & 15;        // 0..15
    const bool aown = tid < 256;

    // phase-A weights: h pair (2*tid, 2*tid+1)
    float2 w1p[OUT];
    if (aown) {
        #pragma unroll
        for (int j = 0; j < OUT; ++j)
            w1p[j] = *(const float2*)(w1 + (size_t)(FF + j) * HD + 2 * tid);
    }
    // phase-B weights: output q, h chunk r*32..r*32+31, both halves resident
    f4 wqp[8], wqv[8];
    #pragma unroll
    for (int s = 0; s < 8; ++s) {
        wqp[s] = *(const f4*)(w2t + (size_t)q * HD + r * 32 + s * 4);
        wqv[s] = *(const f4*)(w2t + (size_t)(OUT + q) * HD + r * 32 + s * 4);
    }
    float b2p = b2[q], b2v = b2[OUT + q];

    float pvf = provide[0] ? 1.0f : 0.0f;
    float myq = pvf * jang[(size_t)(b * OUT + q) * TT + 32];
    if (r == 0) prev_lds[0][q] = myq;

    const float* Xrow = X + (size_t)b * NT * HD + 2 * tid;
    float* predrow = preds + (size_t)b * NT * OUT;
    float2 xc = {0.f, 0.f}, xn = {0.f, 0.f};
    if (aown) {
        xc = *(const float2*)(Xrow);
        xn = *(const float2*)(Xrow + HD);
    }
    __syncthreads();

    for (int t = 0; t < NPS; ++t) { SCAN_STEP(t, true) }
    for (int t = NPS; t < NT; ++t) { SCAN_STEP(t, false) }
}

// ---------------- output kernels ----------------
__global__ void k_up(const float* __restrict__ preds, float* __restrict__ outp) {
    __shared__ float row[NT];
    int rc = blockIdx.x;  // b*20 + ch
    int bq = rc / OUT, ch = rc - bq * OUT;
    int tid = threadIdx.x;
    if (tid < NT) row[tid] = preds[(size_t)(bq * NT + tid) * OUT + ch];
    __syncthreads();
    const float scale = (float)NT / (float)TOUT;
    for (int i = tid; i < TOUT; i += 256) {
        float src = ((float)i + 0.5f) * scale - 0.5f;
        src = fminf(fmaxf(src, 0.0f), (float)(NT - 1));
        float fl = floorf(src);
        int lo = (int)fl;
        int hi = lo + 1; if (hi > NT - 1) hi = NT - 1;
        float w = src - fl;
        outp[(size_t)rc * TOUT + i] = row[lo] * (1.0f - w) + row[hi] * w;
    }
}

__global__ void k_ja(const float* __restrict__ jang, float* __restrict__ outp) {
    int rc = blockIdx.x;
    int tid = threadIdx.x;
    for (int i = tid; i < TOUT; i += 256)
        outp[(size_t)rc * TOUT + i] = jang[(size_t)rc * TT + 32 + i];
}

__global__ void k_mask(const unsigned char* __restrict__ m, float* __restrict__ outp) {
    int b = blockIdx.x;
    int tid = threadIdx.x;
    for (int i = tid; i < TOUT; i += 256)
        outp[(size_t)b * TOUT + i] = m[(size_t)b * TT + 32 + i] ? 1.0f : 0.0f;
}

extern "C" void kernel_launch(void* const* d_in, const int* in_sizes, int n_in,
                              void* d_out, int out_size, void* d_ws, size_t ws_size,
                              hipStream_t stream) {
    const float* emg     = (const float*)d_in[0];
    const float* jang    = (const float*)d_in[1];
    const unsigned char* msk = (const unsigned char*)d_in[2];
    const int*   provide = (const int*)d_in[3];
    const float* conv_w  = (const float*)d_in[4];
    const float* conv_b  = (const float*)d_in[5];
    const float* w1      = (const float*)d_in[6];
    const float* b1      = (const float*)d_in[7];
    const float* w2      = (const float*)d_in[8];
    const float* b2      = (const float*)d_in[9];
    float* out = (float*)d_out;
    float* ws  = (float*)d_ws;

    float* CW    = ws + WS_CW;
    float* bX    = ws + WS_BX;
    float* X     = ws + WS_X;
    float* preds = ws + WS_PR;
    float* Et    = ws + WS_ET;
    float* w2t   = ws + WS_W2T;

    hipLaunchKernelGGL(k_e,    dim3(KP, (MM + 255) / 256), dim3(256), 0, stream, emg, Et);
    hipLaunchKernelGGL(k_cw2,  dim3((CJ + 63) / 64, HD / 64), dim3(256), 0, stream, conv_w, w1, CW);
    hipLaunchKernelGGL(k_bx,   dim3(1), dim3(HD), 0, stream, conv_b, w1, b1, bX);
    hipLaunchKernelGGL(k_w2t,  dim3(2 * OUT), dim3(HD), 0, stream, w2, w2t);
    hipLaunchKernelGGL(k_x6,   dim3(MM / 64, HD / 64), dim3(128), 0, stream, Et, CW, bX, X);
    hipLaunchKernelGGL(k_scan, dim3(BB), dim3(320), 0, stream, X, w1, w2t, b2, jang, provide, preds);
    hipLaunchKernelGGL(k_up,   dim3(BB * OUT), dim3(256), 0, stream, preds, out);
    hipLaunchKernelGGL(k_ja,   dim3(BB * OUT), dim3(256), 0, stream, jang, out + (size_t)BB * OUT * TOUT);
    hipLaunchKernelGGL(k_mask, dim3(BB), dim3(256), 0, stream, msk, out + (size_t)2 * BB * OUT * TOUT);
}